// Round 1
// baseline (971.966 us; speedup 1.0000x reference)
//
#include <hip/hip_runtime.h>
#include <hip/hip_bf16.h>
#include <stdint.h>

#define SEQ 2048
#define BATCH 2
#define NTOK (SEQ * BATCH)   // 4096
#define HID 2048
#define NQH 16
#define NKVH 4
#define HD 128
#define KVD 512              // NKVH * HD

typedef __bf16 bf16x8 __attribute__((ext_vector_type(8)));
typedef float f32x4 __attribute__((ext_vector_type(4)));

__device__ __forceinline__ unsigned short f2bf(float f) {
    uint32_t u = __builtin_bit_cast(uint32_t, f);
    uint32_t r = (u + 0x7fffu + ((u >> 16) & 1u)) >> 16;
    return (unsigned short)r;
}

// ---------------- fp32 -> bf16 convert (vectorized) ----------------
__global__ void cvt_f32_bf16(const float* __restrict__ in, unsigned short* __restrict__ out, int n4) {
    int i = blockIdx.x * blockDim.x + threadIdx.x;
    int stride = gridDim.x * blockDim.x;
    for (; i < n4; i += stride) {
        float4 v = ((const float4*)in)[i];
        ushort4 o;
        o.x = f2bf(v.x); o.y = f2bf(v.y); o.z = f2bf(v.z); o.w = f2bf(v.w);
        ((ushort4*)out)[i] = o;
    }
}

// ------------- W [K][N] fp32  ->  Wt [N][K=2048] bf16 --------------
__global__ __launch_bounds__(256) void transpose_w(const float* __restrict__ W,
                                                   unsigned short* __restrict__ Wt, int N) {
    __shared__ unsigned short tile[64][72];
    const int k0 = blockIdx.x * 64, n0 = blockIdx.y * 64;
    const int t = threadIdx.x;
    const int r = t >> 4;          // 0..15
    const int c4 = (t & 15) * 4;   // 0..60
    #pragma unroll
    for (int i = 0; i < 4; i++) {
        int row = r + i * 16;
        float4 v = *(const float4*)&W[(size_t)(k0 + row) * N + n0 + c4];
        tile[row][c4 + 0] = f2bf(v.x);
        tile[row][c4 + 1] = f2bf(v.y);
        tile[row][c4 + 2] = f2bf(v.z);
        tile[row][c4 + 3] = f2bf(v.w);
    }
    __syncthreads();
    #pragma unroll
    for (int i = 0; i < 4; i++) {
        int nrow = r + i * 16;
        ushort4 o;
        o.x = tile[c4 + 0][nrow];
        o.y = tile[c4 + 1][nrow];
        o.z = tile[c4 + 2][nrow];
        o.w = tile[c4 + 3][nrow];
        *(ushort4*)&Wt[(size_t)(n0 + nrow) * HID + k0 + c4] = o;
    }
}

// ---------------- bf16 TN GEMM: C[M,N] = A[M,K] * Bt[N,K]^T ----------------
// MODE 0: Q proj  -> bf16 out1[M,2048], (acc+bias)*softmax_scale
// MODE 1: KV fused (N=1024): col<512 -> K bf16 out1[M,512]; col>=512 -> Vt bf16 out2[B][512][SEQ]
// MODE 3: O proj  -> fp32 out1[M,2048], acc+bias
template <int MODE>
__global__ __launch_bounds__(256) void gemm_tn(const unsigned short* __restrict__ A,
                                               const unsigned short* __restrict__ Bt,
                                               const float* __restrict__ bias,
                                               const float* __restrict__ bias2,
                                               void* __restrict__ out1,
                                               void* __restrict__ out2) {
    __shared__ unsigned short Asm[128 * 64];
    __shared__ unsigned short Bsm[128 * 64];
    const int m0 = blockIdx.x * 128;
    const int n0 = blockIdx.y * 128;
    const int t = threadIdx.x;
    const int lane = t & 63, w = t >> 6;
    const int wr = (w >> 1) * 64, wc = (w & 1) * 64;
    const int l16 = lane & 15, lg = lane >> 4;

    f32x4 acc[4][4] = {};

    uint4 aReg[4], bReg[4];
    auto loadTile = [&](int k0) {
        #pragma unroll
        for (int i = 0; i < 4; i++) {
            int cidx = t + i * 256;
            int row = cidx >> 3, col8 = (cidx & 7) * 8;
            aReg[i] = *(const uint4*)&A[(size_t)(m0 + row) * HID + k0 + col8];
            bReg[i] = *(const uint4*)&Bt[(size_t)(n0 + row) * HID + k0 + col8];
        }
    };
    loadTile(0);
    for (int kt = 0; kt < HID / 64; kt++) {
        __syncthreads();
        #pragma unroll
        for (int i = 0; i < 4; i++) {
            int cidx = t + i * 256;
            *(uint4*)&Asm[cidx * 8] = aReg[i];
            *(uint4*)&Bsm[cidx * 8] = bReg[i];
        }
        if (kt < HID / 64 - 1) loadTile((kt + 1) * 64);
        __syncthreads();
        #pragma unroll
        for (int kk = 0; kk < 2; kk++) {
            bf16x8 af[4], bfr[4];
            #pragma unroll
            for (int m = 0; m < 4; m++)
                af[m] = *(const bf16x8*)&Asm[(wr + m * 16 + l16) * 64 + kk * 32 + lg * 8];
            #pragma unroll
            for (int n = 0; n < 4; n++)
                bfr[n] = *(const bf16x8*)&Bsm[(wc + n * 16 + l16) * 64 + kk * 32 + lg * 8];
            #pragma unroll
            for (int m = 0; m < 4; m++)
                #pragma unroll
                for (int n = 0; n < 4; n++)
                    acc[m][n] = __builtin_amdgcn_mfma_f32_16x16x32_bf16(af[m], bfr[n], acc[m][n], 0, 0, 0);
        }
    }
    // epilogue
    #pragma unroll
    for (int m = 0; m < 4; m++) {
        int row = m0 + wr + m * 16 + lg * 4;
        #pragma unroll
        for (int n = 0; n < 4; n++) {
            int col = n0 + wc + n * 16 + l16;
            #pragma unroll
            for (int r = 0; r < 4; r++) {
                float v = acc[m][n][r];
                int rr = row + r;
                if constexpr (MODE == 0) {
                    v = (v + bias[col]) * 0.08838834764831845f;
                    ((unsigned short*)out1)[(size_t)rr * HID + col] = f2bf(v);
                } else if constexpr (MODE == 1) {
                    if (col < 512) {
                        v += bias[col];
                        ((unsigned short*)out1)[(size_t)rr * KVD + col] = f2bf(v);
                    } else {
                        int c2 = col - 512;
                        v += bias2[c2];
                        int b = rr >> 11, s = rr & (SEQ - 1);
                        ((unsigned short*)out2)[((size_t)b * KVD + c2) * SEQ + s] = f2bf(v);
                    }
                } else {
                    v += bias[col];
                    ((float*)out1)[(size_t)rr * HID + col] = v;
                }
            }
        }
    }
}

// ---------------- causal GQA flash attention ----------------
// grid: (SEQ/64, BATCH*NQH), block 256. Wave w handles q rows qt*64 + w*16 .. +15.
__global__ __launch_bounds__(256) void attn(const unsigned short* __restrict__ Q,
                                            const unsigned short* __restrict__ K,
                                            const unsigned short* __restrict__ Vt,
                                            unsigned short* __restrict__ ctx) {
    __shared__ unsigned short Pl[4][16 * 64];
    const int qt = blockIdx.x;
    const int bh = blockIdx.y;
    const int b = bh >> 4, h = bh & 15, hk = h >> 2;
    const int t = threadIdx.x, w = t >> 6, lane = t & 63;
    const int l16 = lane & 15, lg = lane >> 4;
    const int qw = qt * 64 + w * 16;                 // within-seq q row base for wave
    const size_t qrowbase = (size_t)b * SEQ + qw;

    bf16x8 qf[4];
    #pragma unroll
    for (int kk = 0; kk < 4; kk++)
        qf[kk] = *(const bf16x8*)&Q[(qrowbase + l16) * HID + h * HD + kk * 32 + lg * 8];

    f32x4 oacc[8] = {};
    float mrow[4] = {-1e30f, -1e30f, -1e30f, -1e30f};
    float lrow[4] = {0.f, 0.f, 0.f, 0.f};

    const unsigned short* Kb = K + (size_t)b * SEQ * KVD + hk * HD;
    const unsigned short* Vb = Vt + ((size_t)b * KVD + hk * HD) * SEQ;
    unsigned short* Pw = &Pl[w][0];

    const int ntile = qt + 1;
    for (int kt = 0; kt < ntile; kt++) {
        const int kvb = kt * 64;
        f32x4 s[4] = {};
        #pragma unroll
        for (int kk = 0; kk < 4; kk++) {
            #pragma unroll
            for (int tt = 0; tt < 4; tt++) {
                bf16x8 kf = *(const bf16x8*)&Kb[(size_t)(kvb + tt * 16 + l16) * KVD + kk * 32 + lg * 8];
                s[tt] = __builtin_amdgcn_mfma_f32_16x16x32_bf16(qf[kk], kf, s[tt], 0, 0, 0);
            }
        }
        if (kt == ntile - 1) {  // diagonal tile: causal mask
            #pragma unroll
            for (int tt = 0; tt < 4; tt++)
                #pragma unroll
                for (int r = 0; r < 4; r++) {
                    int qr = qw + lg * 4 + r;
                    int kc = kvb + tt * 16 + l16;
                    if (kc > qr) s[tt][r] = -1e30f;
                }
        }
        // online softmax (rows live in 16-lane groups)
        float mx[4], sf[4], rs[4];
        #pragma unroll
        for (int r = 0; r < 4; r++) {
            mx[r] = fmaxf(fmaxf(s[0][r], s[1][r]), fmaxf(s[2][r], s[3][r]));
            #pragma unroll
            for (int d = 1; d < 16; d <<= 1)
                mx[r] = fmaxf(mx[r], __shfl_xor(mx[r], d));
            float mn = fmaxf(mrow[r], mx[r]);
            sf[r] = __expf(mrow[r] - mn);
            mrow[r] = mn;
            rs[r] = 0.f;
        }
        #pragma unroll
        for (int tt = 0; tt < 4; tt++) {
            #pragma unroll
            for (int r = 0; r < 4; r++) {
                float p = __expf(s[tt][r] - mrow[r]);
                rs[r] += p;
                Pw[(lg * 4 + r) * 64 + tt * 16 + l16] = f2bf(p);
            }
        }
        #pragma unroll
        for (int r = 0; r < 4; r++) {
            #pragma unroll
            for (int d = 1; d < 16; d <<= 1)
                rs[r] += __shfl_xor(rs[r], d);
            lrow[r] = lrow[r] * sf[r] + rs[r];
        }
        #pragma unroll
        for (int f = 0; f < 8; f++)
            #pragma unroll
            for (int r = 0; r < 4; r++)
                oacc[f][r] *= sf[r];
        asm volatile("" ::: "memory");  // P LDS write (ushort) -> read (vector): no reorder
        #pragma unroll
        for (int kk2 = 0; kk2 < 2; kk2++) {
            bf16x8 pf = *(const bf16x8*)&Pw[l16 * 64 + kk2 * 32 + lg * 8];
            #pragma unroll
            for (int f = 0; f < 8; f++) {
                bf16x8 vf = *(const bf16x8*)&Vb[(size_t)(f * 16 + l16) * SEQ + kvb + kk2 * 32 + lg * 8];
                oacc[f] = __builtin_amdgcn_mfma_f32_16x16x32_bf16(pf, vf, oacc[f], 0, 0, 0);
            }
        }
    }
    // epilogue: ctx[token][h*128 + d] bf16
    #pragma unroll
    for (int f = 0; f < 8; f++)
        #pragma unroll
        for (int r = 0; r < 4; r++) {
            float v = oacc[f][r] / lrow[r];
            ctx[(qrowbase + lg * 4 + r) * HID + h * HD + f * 16 + l16] = f2bf(v);
        }
}

extern "C" void kernel_launch(void* const* d_in, const int* in_sizes, int n_in,
                              void* d_out, int out_size, void* d_ws, size_t ws_size,
                              hipStream_t stream) {
    const float* X  = (const float*)d_in[0];
    const float* Wq = (const float*)d_in[1];
    const float* bq = (const float*)d_in[2];
    const float* Wk = (const float*)d_in[3];
    const float* bk = (const float*)d_in[4];
    const float* Wv = (const float*)d_in[5];
    const float* bv = (const float*)d_in[6];
    const float* Wo = (const float*)d_in[7];
    const float* bo = (const float*)d_in[8];
    float* out = (float*)d_out;

    const size_t MB = 1u << 20;
    char* ws = (char*)d_ws;
    if (ws_size < 76 * MB) return;  // insufficient workspace -> visible failure
    unsigned short* Xb   = (unsigned short*)(ws + 0 * MB);    // [4096][2048] bf16
    unsigned short* Wqt  = (unsigned short*)(ws + 16 * MB);   // [2048][2048]
    unsigned short* Wkvt = (unsigned short*)(ws + 24 * MB);   // [1024][2048]
    unsigned short* Wot  = (unsigned short*)(ws + 28 * MB);   // [2048][2048]
    unsigned short* Qb   = (unsigned short*)(ws + 36 * MB);   // [4096][2048]
    unsigned short* Kb   = (unsigned short*)(ws + 52 * MB);   // [4096][512]
    unsigned short* Vtb  = (unsigned short*)(ws + 56 * MB);   // [2][512][2048]
    unsigned short* Ctx  = (unsigned short*)(ws + 60 * MB);   // [4096][2048]

    cvt_f32_bf16<<<2048, 256, 0, stream>>>(X, Xb, NTOK * HID / 4);
    transpose_w<<<dim3(HID / 64, HID / 64), 256, 0, stream>>>(Wq, Wqt, HID);
    transpose_w<<<dim3(HID / 64, KVD / 64), 256, 0, stream>>>(Wk, Wkvt, KVD);
    transpose_w<<<dim3(HID / 64, KVD / 64), 256, 0, stream>>>(Wv, Wkvt + (size_t)512 * HID, KVD);
    transpose_w<<<dim3(HID / 64, HID / 64), 256, 0, stream>>>(Wo, Wot, HID);

    gemm_tn<0><<<dim3(NTOK / 128, HID / 128), 256, 0, stream>>>(Xb, Wqt, bq, nullptr, Qb, nullptr);
    gemm_tn<1><<<dim3(NTOK / 128, 1024 / 128), 256, 0, stream>>>(Xb, Wkvt, bk, bv, Kb, Vtb);

    attn<<<dim3(SEQ / 64, BATCH * NQH), 256, 0, stream>>>(Qb, Kb, Vtb, Ctx);

    gemm_tn<3><<<dim3(NTOK / 128, HID / 128), 256, 0, stream>>>(Ctx, Wot, bo, nullptr, out, nullptr);
}

// Round 2
// 296.004 us; speedup vs baseline: 3.2836x; 3.2836x over previous
//
#include <hip/hip_runtime.h>
#include <hip/hip_bf16.h>
#include <stdint.h>

#define SEQ 2048
#define BATCH 2
#define NTOK (SEQ * BATCH)   // 4096
#define HID 2048
#define NQH 16
#define NKVH 4
#define HD 128
#define KVD 512              // NKVH * HD

typedef __bf16 bf16x8 __attribute__((ext_vector_type(8)));
typedef float f32x4 __attribute__((ext_vector_type(4)));
typedef unsigned int u32;

__device__ __forceinline__ unsigned short f2bf(float f) {
    uint32_t u = __builtin_bit_cast(uint32_t, f);
    uint32_t r = (u + 0x7fffu + ((u >> 16) & 1u)) >> 16;
    return (unsigned short)r;
}

// async global->LDS, 16B per lane. lds ptr must be wave-uniform (HW appends lane*16).
__device__ __forceinline__ void gload16(const void* g, void* l) {
    __builtin_amdgcn_global_load_lds((const __attribute__((address_space(1))) u32*)g,
                                     (__attribute__((address_space(3))) u32*)l, 16, 0, 0);
}

// ---------------- fp32 -> bf16 convert (vectorized) ----------------
__global__ void cvt_f32_bf16(const float* __restrict__ in, unsigned short* __restrict__ out, int n4) {
    int i = blockIdx.x * blockDim.x + threadIdx.x;
    int stride = gridDim.x * blockDim.x;
    for (; i < n4; i += stride) {
        float4 v = ((const float4*)in)[i];
        ushort4 o;
        o.x = f2bf(v.x); o.y = f2bf(v.y); o.z = f2bf(v.z); o.w = f2bf(v.w);
        ((ushort4*)out)[i] = o;
    }
}

// ------------- W [K][N] fp32  ->  Wt [N][K=2048] bf16 --------------
__global__ __launch_bounds__(256) void transpose_w(const float* __restrict__ W,
                                                   unsigned short* __restrict__ Wt, int N) {
    __shared__ unsigned short tile[64][72];
    const int k0 = blockIdx.x * 64, n0 = blockIdx.y * 64;
    const int t = threadIdx.x;
    const int r = t >> 4;          // 0..15
    const int c4 = (t & 15) * 4;   // 0..60
    #pragma unroll
    for (int i = 0; i < 4; i++) {
        int row = r + i * 16;
        float4 v = *(const float4*)&W[(size_t)(k0 + row) * N + n0 + c4];
        tile[row][c4 + 0] = f2bf(v.x);
        tile[row][c4 + 1] = f2bf(v.y);
        tile[row][c4 + 2] = f2bf(v.z);
        tile[row][c4 + 3] = f2bf(v.w);
    }
    __syncthreads();
    #pragma unroll
    for (int i = 0; i < 4; i++) {
        int nrow = r + i * 16;
        ushort4 o;
        o.x = tile[c4 + 0][nrow];
        o.y = tile[c4 + 1][nrow];
        o.z = tile[c4 + 2][nrow];
        o.w = tile[c4 + 3][nrow];
        *(ushort4*)&Wt[(size_t)(n0 + nrow) * HID + k0 + c4] = o;
    }
}

// ---------------- bf16 TN GEMM: C[M,N] = A[M,K] * Bt[N,K]^T ----------------
// global_load_lds staging, double-buffered, source-swizzled (chunk ^= row&7).
// MODE 0: Q proj  -> bf16 out1[M,2048], (acc+bias)*softmax_scale
// MODE 1: KV fused (N=1024): col<512 -> K bf16 out1[M,512]; col>=512 -> Vt bf16 out2[B][512][SEQ]
// MODE 3: O proj  -> fp32 out1[M,2048], acc+bias
template <int MODE>
__global__ __launch_bounds__(256) void gemm_tn(const unsigned short* __restrict__ A,
                                               const unsigned short* __restrict__ Bt,
                                               const float* __restrict__ bias,
                                               const float* __restrict__ bias2,
                                               void* __restrict__ out1,
                                               void* __restrict__ out2) {
    __shared__ unsigned short Asm[2][128 * 64];
    __shared__ unsigned short Bsm[2][128 * 64];
    const int m0 = blockIdx.x * 128;
    const int n0 = blockIdx.y * 128;
    const int t = threadIdx.x;
    const int lane = t & 63, w = t >> 6;
    const int wr = (w >> 1) * 64, wc = (w & 1) * 64;
    const int l16 = lane & 15, lg = lane >> 4;

    f32x4 acc[4][4] = {};

    auto stage = [&](int buf, int kt) {
        const int k0 = kt * 64;
        #pragma unroll
        for (int it = 0; it < 4; it++) {
            int base = it * 256 + w * 64;          // wave-uniform chunk base
            int qc = base + lane;                  // this lane's chunk
            int row = qc >> 3, c = qc & 7;
            int col = ((c ^ (row & 7)) << 3);
            gload16(&A[(size_t)(m0 + row) * HID + k0 + col], (char*)&Asm[buf][0] + base * 16);
            gload16(&Bt[(size_t)(n0 + row) * HID + k0 + col], (char*)&Bsm[buf][0] + base * 16);
        }
    };

    stage(0, 0);
    __syncthreads();
    int buf = 0;
    for (int kt = 0; kt < HID / 64; kt++) {
        if (kt < HID / 64 - 1) stage(buf ^ 1, kt + 1);
        const char* Ab = (const char*)&Asm[buf][0];
        const char* Bb = (const char*)&Bsm[buf][0];
        #pragma unroll
        for (int kk = 0; kk < 2; kk++) {
            bf16x8 af[4], bfr[4];
            #pragma unroll
            for (int m = 0; m < 4; m++) {
                int row = wr + m * 16 + l16;
                af[m] = *(const bf16x8*)(Ab + row * 128 + (((kk * 4 + lg) ^ (row & 7)) << 4));
            }
            #pragma unroll
            for (int n = 0; n < 4; n++) {
                int row = wc + n * 16 + l16;
                bfr[n] = *(const bf16x8*)(Bb + row * 128 + (((kk * 4 + lg) ^ (row & 7)) << 4));
            }
            #pragma unroll
            for (int m = 0; m < 4; m++)
                #pragma unroll
                for (int n = 0; n < 4; n++)
                    acc[m][n] = __builtin_amdgcn_mfma_f32_16x16x32_bf16(af[m], bfr[n], acc[m][n], 0, 0, 0);
        }
        __syncthreads();
        buf ^= 1;
    }
    // epilogue
    #pragma unroll
    for (int m = 0; m < 4; m++) {
        int row = m0 + wr + m * 16 + lg * 4;
        #pragma unroll
        for (int n = 0; n < 4; n++) {
            int col = n0 + wc + n * 16 + l16;
            #pragma unroll
            for (int r = 0; r < 4; r++) {
                float v = acc[m][n][r];
                int rr = row + r;
                if constexpr (MODE == 0) {
                    v = (v + bias[col]) * 0.08838834764831845f;
                    ((unsigned short*)out1)[(size_t)rr * HID + col] = f2bf(v);
                } else if constexpr (MODE == 1) {
                    if (col < 512) {
                        v += bias[col];
                        ((unsigned short*)out1)[(size_t)rr * KVD + col] = f2bf(v);
                    } else {
                        int c2 = col - 512;
                        v += bias2[c2];
                        int b = rr >> 11, s = rr & (SEQ - 1);
                        ((unsigned short*)out2)[((size_t)b * KVD + c2) * SEQ + s] = f2bf(v);
                    }
                } else {
                    v += bias[col];
                    ((float*)out1)[(size_t)rr * HID + col] = v;
                }
            }
        }
    }
}

// ---------------- causal GQA flash attention ----------------
// grid: (SEQ/128, BATCH*NQH), 512 threads (8 waves x 16 q-rows = 128-row q-tile).
// K/V staged in double-buffered LDS via global_load_lds (source-swizzled).
__global__ __launch_bounds__(512, 4) void attn(const unsigned short* __restrict__ Q,
                                               const unsigned short* __restrict__ K,
                                               const unsigned short* __restrict__ Vt,
                                               unsigned short* __restrict__ ctx) {
    __shared__ unsigned short Ksm[2][64 * 128];   // [s=64][d=128], chunk-swizzled
    __shared__ unsigned short Vsm[2][128 * 64];   // [d=128][s=64], chunk-swizzled
    __shared__ unsigned short Pl[8][16 * 64];     // per-wave P, chunk-swizzled
    const int qt = (SEQ / 128 - 1) - blockIdx.x;  // heavy q-tiles dispatch first
    const int bh = blockIdx.y;
    const int b = bh >> 4, h = bh & 15, hk = h >> 2;
    const int t = threadIdx.x, w = t >> 6, lane = t & 63;
    const int l16 = lane & 15, lg = lane >> 4;
    const int qw = qt * 128 + w * 16;
    const size_t qrowbase = (size_t)b * SEQ + qw;

    const unsigned short* Kg = K + (size_t)b * SEQ * KVD + hk * HD;
    const unsigned short* Vg = Vt + ((size_t)b * KVD + hk * HD) * SEQ;

    bf16x8 qf[4];
    #pragma unroll
    for (int kk = 0; kk < 4; kk++)
        qf[kk] = *(const bf16x8*)&Q[(qrowbase + l16) * HID + h * HD + kk * 32 + lg * 8];

    f32x4 oacc[8] = {};
    float mrow[4] = {-1e30f, -1e30f, -1e30f, -1e30f};
    float lrow[4] = {0.f, 0.f, 0.f, 0.f};
    char* Pw = (char*)&Pl[w][0];

    const int ntile = (qt + 1) * 2;

    auto stage = [&](int buf, int kt) {
        const int kvb = kt * 64;
        #pragma unroll
        for (int it = 0; it < 2; it++) {
            int base = it * 512 + w * 64;          // wave-uniform chunk base
            int qc = base + lane;
            {   // K tile: 64 rows x 16 chunks
                int row = qc >> 4, c = qc & 15;
                gload16(&Kg[(size_t)(kvb + row) * KVD + ((c ^ (row & 7)) << 3)],
                        (char*)&Ksm[buf][0] + base * 16);
            }
            {   // V tile: 128 rows x 8 chunks
                int row = qc >> 3, c = qc & 7;
                gload16(&Vg[(size_t)row * SEQ + kvb + ((c ^ (row & 7)) << 3)],
                        (char*)&Vsm[buf][0] + base * 16);
            }
        }
    };

    stage(0, 0);
    __syncthreads();
    int buf = 0;
    for (int kt = 0; kt < ntile; kt++) {
        const int kvb = kt * 64;
        if (kt < ntile - 1) stage(buf ^ 1, kt + 1);
        if (kvb <= qw + 15) {   // not fully masked for this wave
            const char* Kb = (const char*)&Ksm[buf][0];
            const char* Vb = (const char*)&Vsm[buf][0];
            f32x4 s4[4] = {};
            #pragma unroll
            for (int kk = 0; kk < 4; kk++) {
                #pragma unroll
                for (int tt = 0; tt < 4; tt++) {
                    int srow = tt * 16 + l16;
                    bf16x8 kf = *(const bf16x8*)(Kb + srow * 256 + (((kk * 4 + lg) ^ (srow & 7)) << 4));
                    s4[tt] = __builtin_amdgcn_mfma_f32_16x16x32_bf16(qf[kk], kf, s4[tt], 0, 0, 0);
                }
            }
            if (kvb + 63 > qw) {  // diagonal: causal mask
                #pragma unroll
                for (int tt = 0; tt < 4; tt++)
                    #pragma unroll
                    for (int r = 0; r < 4; r++) {
                        int qr = qw + lg * 4 + r;
                        int kc = kvb + tt * 16 + l16;
                        if (kc > qr) s4[tt][r] = -1e30f;
                    }
            }
            // online softmax (rows live across the 16 lanes of each lg group)
            float mx[4], sf[4], rs[4];
            #pragma unroll
            for (int r = 0; r < 4; r++) {
                mx[r] = fmaxf(fmaxf(s4[0][r], s4[1][r]), fmaxf(s4[2][r], s4[3][r]));
                #pragma unroll
                for (int d = 1; d < 16; d <<= 1)
                    mx[r] = fmaxf(mx[r], __shfl_xor(mx[r], d));
                float mn = fmaxf(mrow[r], mx[r]);
                sf[r] = __expf(mrow[r] - mn);
                mrow[r] = mn;
                rs[r] = 0.f;
            }
            #pragma unroll
            for (int tt = 0; tt < 4; tt++) {
                #pragma unroll
                for (int r = 0; r < 4; r++) {
                    float p = __expf(s4[tt][r] - mrow[r]);
                    rs[r] += p;
                    int prow = lg * 4 + r, pcol = tt * 16 + l16;
                    *(unsigned short*)(Pw + prow * 128 + ((pcol * 2) ^ ((prow & 7) << 4))) = f2bf(p);
                }
            }
            #pragma unroll
            for (int r = 0; r < 4; r++) {
                #pragma unroll
                for (int d = 1; d < 16; d <<= 1)
                    rs[r] += __shfl_xor(rs[r], d);
                lrow[r] = lrow[r] * sf[r] + rs[r];
            }
            #pragma unroll
            for (int f = 0; f < 8; f++)
                #pragma unroll
                for (int r = 0; r < 4; r++)
                    oacc[f][r] *= sf[r];
            asm volatile("" ::: "memory");  // order P ds_write before ds_read
            #pragma unroll
            for (int kk2 = 0; kk2 < 2; kk2++) {
                bf16x8 pf = *(const bf16x8*)(Pw + l16 * 128 + (((kk2 * 4 + lg) ^ (l16 & 7)) << 4));
                #pragma unroll
                for (int f = 0; f < 8; f++) {
                    int vrow = f * 16 + l16;
                    bf16x8 vf = *(const bf16x8*)(Vb + vrow * 128 + (((kk2 * 4 + lg) ^ (vrow & 7)) << 4));
                    oacc[f] = __builtin_amdgcn_mfma_f32_16x16x32_bf16(pf, vf, oacc[f], 0, 0, 0);
                }
            }
        }
        __syncthreads();
        buf ^= 1;
    }
    // epilogue: ctx[token][h*128 + d] bf16
    #pragma unroll
    for (int f = 0; f < 8; f++)
        #pragma unroll
        for (int r = 0; r < 4; r++) {
            float v = oacc[f][r] / lrow[r];
            ctx[(qrowbase + lg * 4 + r) * HID + h * HD + f * 16 + l16] = f2bf(v);
        }
}

extern "C" void kernel_launch(void* const* d_in, const int* in_sizes, int n_in,
                              void* d_out, int out_size, void* d_ws, size_t ws_size,
                              hipStream_t stream) {
    const float* X  = (const float*)d_in[0];
    const float* Wq = (const float*)d_in[1];
    const float* bq = (const float*)d_in[2];
    const float* Wk = (const float*)d_in[3];
    const float* bk = (const float*)d_in[4];
    const float* Wv = (const float*)d_in[5];
    const float* bv = (const float*)d_in[6];
    const float* Wo = (const float*)d_in[7];
    const float* bo = (const float*)d_in[8];
    float* out = (float*)d_out;

    const size_t MB = 1u << 20;
    char* ws = (char*)d_ws;
    if (ws_size < 76 * MB) return;  // insufficient workspace -> visible failure
    unsigned short* Xb   = (unsigned short*)(ws + 0 * MB);    // [4096][2048] bf16
    unsigned short* Wqt  = (unsigned short*)(ws + 16 * MB);   // [2048][2048]
    unsigned short* Wkvt = (unsigned short*)(ws + 24 * MB);   // [1024][2048]
    unsigned short* Wot  = (unsigned short*)(ws + 28 * MB);   // [2048][2048]
    unsigned short* Qb   = (unsigned short*)(ws + 36 * MB);   // [4096][2048]
    unsigned short* Kb   = (unsigned short*)(ws + 52 * MB);   // [4096][512]
    unsigned short* Vtb  = (unsigned short*)(ws + 56 * MB);   // [2][512][2048]
    unsigned short* Ctx  = (unsigned short*)(ws + 60 * MB);   // [4096][2048]

    cvt_f32_bf16<<<2048, 256, 0, stream>>>(X, Xb, NTOK * HID / 4);
    transpose_w<<<dim3(HID / 64, HID / 64), 256, 0, stream>>>(Wq, Wqt, HID);
    transpose_w<<<dim3(HID / 64, KVD / 64), 256, 0, stream>>>(Wk, Wkvt, KVD);
    transpose_w<<<dim3(HID / 64, KVD / 64), 256, 0, stream>>>(Wv, Wkvt + (size_t)512 * HID, KVD);
    transpose_w<<<dim3(HID / 64, HID / 64), 256, 0, stream>>>(Wo, Wot, HID);

    gemm_tn<0><<<dim3(NTOK / 128, HID / 128), 256, 0, stream>>>(Xb, Wqt, bq, nullptr, Qb, nullptr);
    gemm_tn<1><<<dim3(NTOK / 128, 1024 / 128), 256, 0, stream>>>(Xb, Wkvt, bk, bv, Kb, Vtb);

    attn<<<dim3(SEQ / 128, BATCH * NQH), 512, 0, stream>>>(Qb, Kb, Vtb, Ctx);

    gemm_tn<3><<<dim3(NTOK / 128, HID / 128), 256, 0, stream>>>(Ctx, Wot, bo, nullptr, out, nullptr);
}

// Round 3
// 230.487 us; speedup vs baseline: 4.2170x; 1.2843x over previous
//
#include <hip/hip_runtime.h>
#include <hip/hip_bf16.h>
#include <stdint.h>

#define SEQ 2048
#define BATCH 2
#define NTOK (SEQ * BATCH)   // 4096
#define HID 2048
#define NQH 16
#define NKVH 4
#define HD 128
#define KVD 512              // NKVH * HD

typedef __bf16 bf16x8 __attribute__((ext_vector_type(8)));
typedef float f32x4 __attribute__((ext_vector_type(4)));
typedef float f32x16 __attribute__((ext_vector_type(16)));
typedef unsigned int u32;

__device__ __forceinline__ unsigned short f2bf(float f) {
    uint32_t u = __builtin_bit_cast(uint32_t, f);
    uint32_t r = (u + 0x7fffu + ((u >> 16) & 1u)) >> 16;
    return (unsigned short)r;
}

__device__ __forceinline__ u32 cvtpk(float lo, float hi) {
    u32 r;
    asm("v_cvt_pk_bf16_f32 %0, %1, %2" : "=v"(r) : "v"(lo), "v"(hi));
    return r;
}

// async global->LDS, 16B per lane. lds ptr must be wave-uniform (HW appends lane*16).
__device__ __forceinline__ void gload16(const void* g, void* l) {
    __builtin_amdgcn_global_load_lds((const __attribute__((address_space(1))) u32*)g,
                                     (__attribute__((address_space(3))) u32*)l, 16, 0, 0);
}

// ---------------- fp32 -> bf16 convert (vectorized) ----------------
__global__ void cvt_f32_bf16(const float* __restrict__ in, unsigned short* __restrict__ out, int n4) {
    int i = blockIdx.x * blockDim.x + threadIdx.x;
    int stride = gridDim.x * blockDim.x;
    for (; i < n4; i += stride) {
        float4 v = ((const float4*)in)[i];
        ushort4 o;
        o.x = f2bf(v.x); o.y = f2bf(v.y); o.z = f2bf(v.z); o.w = f2bf(v.w);
        ((ushort4*)out)[i] = o;
    }
}

// ------------- W [K][N] fp32  ->  Wt [N][K=2048] bf16 --------------
__global__ __launch_bounds__(256) void transpose_w(const float* __restrict__ W,
                                                   unsigned short* __restrict__ Wt, int N) {
    __shared__ unsigned short tile[64][72];
    const int k0 = blockIdx.x * 64, n0 = blockIdx.y * 64;
    const int t = threadIdx.x;
    const int r = t >> 4;          // 0..15
    const int c4 = (t & 15) * 4;   // 0..60
    #pragma unroll
    for (int i = 0; i < 4; i++) {
        int row = r + i * 16;
        float4 v = *(const float4*)&W[(size_t)(k0 + row) * N + n0 + c4];
        tile[row][c4 + 0] = f2bf(v.x);
        tile[row][c4 + 1] = f2bf(v.y);
        tile[row][c4 + 2] = f2bf(v.z);
        tile[row][c4 + 3] = f2bf(v.w);
    }
    __syncthreads();
    #pragma unroll
    for (int i = 0; i < 4; i++) {
        int nrow = r + i * 16;
        ushort4 o;
        o.x = tile[c4 + 0][nrow];
        o.y = tile[c4 + 1][nrow];
        o.z = tile[c4 + 2][nrow];
        o.w = tile[c4 + 3][nrow];
        *(ushort4*)&Wt[(size_t)(n0 + nrow) * HID + k0 + c4] = o;
    }
}

// ---------------- bf16 TN GEMM: C[M,N] = A[M,K] * Bt[N,K]^T ----------------
template <int MODE>
__global__ __launch_bounds__(256) void gemm_tn(const unsigned short* __restrict__ A,
                                               const unsigned short* __restrict__ Bt,
                                               const float* __restrict__ bias,
                                               const float* __restrict__ bias2,
                                               void* __restrict__ out1,
                                               void* __restrict__ out2) {
    __shared__ unsigned short Asm[2][128 * 64];
    __shared__ unsigned short Bsm[2][128 * 64];
    const int m0 = blockIdx.x * 128;
    const int n0 = blockIdx.y * 128;
    const int t = threadIdx.x;
    const int lane = t & 63, w = t >> 6;
    const int wr = (w >> 1) * 64, wc = (w & 1) * 64;
    const int l16 = lane & 15, lg = lane >> 4;

    f32x4 acc[4][4] = {};

    auto stage = [&](int buf, int kt) {
        const int k0 = kt * 64;
        #pragma unroll
        for (int it = 0; it < 4; it++) {
            int base = it * 256 + w * 64;          // wave-uniform chunk base
            int qc = base + lane;                  // this lane's chunk
            int row = qc >> 3, c = qc & 7;
            int col = ((c ^ (row & 7)) << 3);
            gload16(&A[(size_t)(m0 + row) * HID + k0 + col], (char*)&Asm[buf][0] + base * 16);
            gload16(&Bt[(size_t)(n0 + row) * HID + k0 + col], (char*)&Bsm[buf][0] + base * 16);
        }
    };

    stage(0, 0);
    __syncthreads();
    int buf = 0;
    for (int kt = 0; kt < HID / 64; kt++) {
        if (kt < HID / 64 - 1) stage(buf ^ 1, kt + 1);
        const char* Ab = (const char*)&Asm[buf][0];
        const char* Bb = (const char*)&Bsm[buf][0];
        #pragma unroll
        for (int kk = 0; kk < 2; kk++) {
            bf16x8 af[4], bfr[4];
            #pragma unroll
            for (int m = 0; m < 4; m++) {
                int row = wr + m * 16 + l16;
                af[m] = *(const bf16x8*)(Ab + row * 128 + (((kk * 4 + lg) ^ (row & 7)) << 4));
            }
            #pragma unroll
            for (int n = 0; n < 4; n++) {
                int row = wc + n * 16 + l16;
                bfr[n] = *(const bf16x8*)(Bb + row * 128 + (((kk * 4 + lg) ^ (row & 7)) << 4));
            }
            #pragma unroll
            for (int m = 0; m < 4; m++)
                #pragma unroll
                for (int n = 0; n < 4; n++)
                    acc[m][n] = __builtin_amdgcn_mfma_f32_16x16x32_bf16(af[m], bfr[n], acc[m][n], 0, 0, 0);
        }
        __syncthreads();
        buf ^= 1;
    }
    // epilogue
    #pragma unroll
    for (int m = 0; m < 4; m++) {
        int row = m0 + wr + m * 16 + lg * 4;
        #pragma unroll
        for (int n = 0; n < 4; n++) {
            int col = n0 + wc + n * 16 + l16;
            #pragma unroll
            for (int r = 0; r < 4; r++) {
                float v = acc[m][n][r];
                int rr = row + r;
                if constexpr (MODE == 0) {
                    v = (v + bias[col]) * 0.08838834764831845f;
                    ((unsigned short*)out1)[(size_t)rr * HID + col] = f2bf(v);
                } else if constexpr (MODE == 1) {
                    if (col < 512) {
                        v += bias[col];
                        ((unsigned short*)out1)[(size_t)rr * KVD + col] = f2bf(v);
                    } else {
                        int c2 = col - 512;
                        v += bias2[c2];
                        int b = rr >> 11, s = rr & (SEQ - 1);
                        ((unsigned short*)out2)[((size_t)b * KVD + c2) * SEQ + s] = f2bf(v);
                    }
                } else {
                    v += bias[col];
                    ((float*)out1)[(size_t)rr * HID + col] = v;
                }
            }
        }
    }
}

// ---------------- causal GQA flash attention, 32x32 MFMA swapped-operand ----------------
// 1D grid 512 blocks, 256 threads (4 waves x 32 q-rows = 128-row q-tile).
// S^T = mfma(K, Q): lane owns q = lane&31. Softmax in-register. PV: O^T = mfma(V^T, P^T).
__global__ __launch_bounds__(256, 2) void attn(const unsigned short* __restrict__ Q,
                                               const unsigned short* __restrict__ K,
                                               const unsigned short* __restrict__ Vt,
                                               unsigned short* __restrict__ ctx) {
    __shared__ unsigned short Ksm[2][64 * 128];   // [s=64][d=128], slot16 ^= row&7
    __shared__ unsigned short Vsm[2][128 * 64];   // [d=128][s=64], slot16 ^= row&7
    const int n = blockIdx.x;                     // 0..511
    const int qx = n & 15;
    const int qt = (n < 256) ? (15 - qx) : qx;    // complementary pairing across halves
    const int bh = (n >> 4) & 31;
    const int b = bh >> 4, h = bh & 15, hk = h >> 2;
    const int t = threadIdx.x, w = t >> 6, lane = t & 63;
    const int lam = lane & 31, hi = lane >> 5;
    const int qw = qt * 128 + w * 32;             // wave's q-row base
    const int qg = qw + lam;                      // this lane's q row (within seq)
    const size_t qrowbase = (size_t)b * SEQ + qw;

    const unsigned short* Kg = K + (size_t)b * SEQ * KVD + hk * HD;
    const unsigned short* Vg = Vt + ((size_t)b * KVD + hk * HD) * SEQ;

    // Q fragments: B-operand for QK^T. qf[kc] elem j = Q[qg][kc*16 + 8*hi + j]
    bf16x8 qf[8];
    #pragma unroll
    for (int kc = 0; kc < 8; kc++)
        qf[kc] = *(const bf16x8*)&Q[(qrowbase + lam) * HID + h * HD + kc * 16 + hi * 8];

    f32x16 oacc[4] = {};        // O^T[d = dc*32 + krow(r,hi)][q = lam]
    float m = -1e30f, l = 0.f;

    auto stage = [&](int buf, int kt) {
        const int kvb = kt * 64;
        #pragma unroll
        for (int it = 0; it < 4; it++) {
            int base = it * 256 + w * 64;          // wave-uniform chunk base
            int qc = base + lane;
            {   // K tile: 64 rows x 16 slots of 16B
                int row = qc >> 4, c = qc & 15;
                gload16(&Kg[(size_t)(kvb + row) * KVD + ((c ^ (row & 7)) << 3)],
                        (char*)&Ksm[buf][0] + base * 16);
            }
            {   // V^T tile: 128 rows x 8 slots
                int row = qc >> 3, c = qc & 7;
                gload16(&Vg[(size_t)row * SEQ + kvb + ((c ^ (row & 7)) << 3)],
                        (char*)&Vsm[buf][0] + base * 16);
            }
        }
    };

    const int ntile = 2 * qt + 2;
    stage(0, 0);
    __syncthreads();
    int buf = 0;
    for (int kt = 0; kt < ntile; kt++) {
        const int kvb = kt * 64;
        if (kt + 1 < ntile) stage(buf ^ 1, kt + 1);
        if (kvb <= qw + 31) {
            const char* Kb = (const char*)&Ksm[buf][0];
            const char* Vb = (const char*)&Vsm[buf][0];
            // ---- QK^T: S^T[k][q], k in 2 blocks of 32 ----
            f32x16 st0 = {}, st1 = {};
            #pragma unroll
            for (int kc = 0; kc < 8; kc++) {
                int coff = (kc * 32 + hi * 16) ^ ((lam & 7) << 4);
                bf16x8 kf0 = *(const bf16x8*)(Kb + lam * 256 + coff);
                bf16x8 kf1 = *(const bf16x8*)(Kb + (32 + lam) * 256 + coff);
                st0 = __builtin_amdgcn_mfma_f32_32x32x16_bf16(kf0, qf[kc], st0, 0, 0, 0);
                st1 = __builtin_amdgcn_mfma_f32_32x32x16_bf16(kf1, qf[kc], st1, 0, 0, 0);
            }
            // causal mask (diagonal region only)
            if (kvb + 63 > qw) {
                #pragma unroll
                for (int r = 0; r < 16; r++) {
                    int krow = (r & 3) + 8 * (r >> 2) + 4 * hi;
                    if (kvb + krow > qg) st0[r] = -1e30f;
                    if (kvb + 32 + krow > qg) st1[r] = -1e30f;
                }
            }
            // ---- online softmax, fully in-register (q = lam per lane) ----
            float tmax = st0[0];
            #pragma unroll
            for (int r = 1; r < 16; r++) tmax = fmaxf(tmax, st0[r]);
            #pragma unroll
            for (int r = 0; r < 16; r++) tmax = fmaxf(tmax, st1[r]);
            tmax = fmaxf(tmax, __shfl_xor(tmax, 32));
            float mn = fmaxf(m, tmax);
            float sf = __expf(m - mn);
            m = mn;
            float rs = 0.f;
            #pragma unroll
            for (int r = 0; r < 16; r++) { st0[r] = __expf(st0[r] - mn); rs += st0[r]; }
            #pragma unroll
            for (int r = 0; r < 16; r++) { st1[r] = __expf(st1[r] - mn); rs += st1[r]; }
            rs += __shfl_xor(rs, 32);
            l = l * sf + rs;
            #pragma unroll
            for (int dc = 0; dc < 4; dc++)
                #pragma unroll
                for (int r = 0; r < 16; r++) oacc[dc][r] *= sf;
            // ---- pack P to bf16 pairs: pw[kb2][g][0] = (p[4g],p[4g+1]) ----
            u32 pw0[4][2], pw1[4][2];
            #pragma unroll
            for (int g = 0; g < 4; g++) {
                pw0[g][0] = cvtpk(st0[4 * g], st0[4 * g + 1]);
                pw0[g][1] = cvtpk(st0[4 * g + 2], st0[4 * g + 3]);
                pw1[g][0] = cvtpk(st1[4 * g], st1[4 * g + 1]);
                pw1[g][1] = cvtpk(st1[4 * g + 2], st1[4 * g + 3]);
            }
            // ---- PV: O^T += V^T · P^T over 4 k-chunks of 16 ----
            #pragma unroll
            for (int kc = 0; kc < 4; kc++) {
                const u32 (*pw)[2] = (kc >> 1) ? pw1 : pw0;
                int g0 = (kc & 1) * 2;
                u32 own0 = hi ? pw[g0 + 1][0] : pw[g0][0];
                u32 own1 = hi ? pw[g0 + 1][1] : pw[g0][1];
                u32 off0 = hi ? pw[g0][0] : pw[g0 + 1][0];
                u32 off1 = hi ? pw[g0][1] : pw[g0 + 1][1];
                u32 xw0 = __shfl_xor(off0, 32);
                u32 xw1 = __shfl_xor(off1, 32);
                int4 paw;
                paw.x = hi ? xw0 : own0;
                paw.y = hi ? xw1 : own1;
                paw.z = hi ? own0 : xw0;
                paw.w = hi ? own1 : xw1;
                bf16x8 pa = __builtin_bit_cast(bf16x8, paw);
                #pragma unroll
                for (int dc = 0; dc < 4; dc++) {
                    bf16x8 vf = *(const bf16x8*)(Vb + (dc * 32 + lam) * 128 +
                                                 ((kc * 32 + hi * 16) ^ ((lam & 7) << 4)));
                    oacc[dc] = __builtin_amdgcn_mfma_f32_32x32x16_bf16(vf, pa, oacc[dc], 0, 0, 0);
                }
            }
        }
        __syncthreads();
        buf ^= 1;
    }

    // ---- epilogue: transpose O^T through LDS (reuse Ksm), coalesced store ----
    float inv = 1.f / l;
    char* osm = (char*)&Ksm[0][0] + w * 8192;     // per-wave 32 x 256B region
    #pragma unroll
    for (int dc = 0; dc < 4; dc++)
        #pragma unroll
        for (int r = 0; r < 16; r += 2) {
            int d = dc * 32 + (r & 3) + 8 * (r >> 2) + 4 * hi;
            u32 wd = cvtpk(oacc[dc][r] * inv, oacc[dc][r + 1] * inv);
            *(u32*)(osm + lam * 256 + ((d * 2) ^ ((lam & 7) << 4))) = wd;
        }
    __syncthreads();
    const int q2 = lane >> 1, half = lane & 1;
    #pragma unroll
    for (int cc = 0; cc < 8; cc++) {
        bf16x8 v = *(const bf16x8*)(osm + q2 * 256 + (((half * 8 + cc) * 16) ^ ((q2 & 7) << 4)));
        *(bf16x8*)&ctx[(qrowbase + q2) * HID + h * HD + half * 64 + cc * 8] = v;
    }
}

extern "C" void kernel_launch(void* const* d_in, const int* in_sizes, int n_in,
                              void* d_out, int out_size, void* d_ws, size_t ws_size,
                              hipStream_t stream) {
    const float* X  = (const float*)d_in[0];
    const float* Wq = (const float*)d_in[1];
    const float* bq = (const float*)d_in[2];
    const float* Wk = (const float*)d_in[3];
    const float* bk = (const float*)d_in[4];
    const float* Wv = (const float*)d_in[5];
    const float* bv = (const float*)d_in[6];
    const float* Wo = (const float*)d_in[7];
    const float* bo = (const float*)d_in[8];
    float* out = (float*)d_out;

    const size_t MB = 1u << 20;
    char* ws = (char*)d_ws;
    if (ws_size < 76 * MB) return;
    unsigned short* Xb   = (unsigned short*)(ws + 0 * MB);    // [4096][2048] bf16
    unsigned short* Wqt  = (unsigned short*)(ws + 16 * MB);   // [2048][2048]
    unsigned short* Wkvt = (unsigned short*)(ws + 24 * MB);   // [1024][2048]
    unsigned short* Wot  = (unsigned short*)(ws + 28 * MB);   // [2048][2048]
    unsigned short* Qb   = (unsigned short*)(ws + 36 * MB);   // [4096][2048]
    unsigned short* Kb   = (unsigned short*)(ws + 52 * MB);   // [4096][512]
    unsigned short* Vtb  = (unsigned short*)(ws + 56 * MB);   // [2][512][2048]
    unsigned short* Ctx  = (unsigned short*)(ws + 60 * MB);   // [4096][2048]

    cvt_f32_bf16<<<2048, 256, 0, stream>>>(X, Xb, NTOK * HID / 4);
    transpose_w<<<dim3(HID / 64, HID / 64), 256, 0, stream>>>(Wq, Wqt, HID);
    transpose_w<<<dim3(HID / 64, KVD / 64), 256, 0, stream>>>(Wk, Wkvt, KVD);
    transpose_w<<<dim3(HID / 64, KVD / 64), 256, 0, stream>>>(Wv, Wkvt + (size_t)512 * HID, KVD);
    transpose_w<<<dim3(HID / 64, HID / 64), 256, 0, stream>>>(Wo, Wot, HID);

    gemm_tn<0><<<dim3(NTOK / 128, HID / 128), 256, 0, stream>>>(Xb, Wqt, bq, nullptr, Qb, nullptr);
    gemm_tn<1><<<dim3(NTOK / 128, 1024 / 128), 256, 0, stream>>>(Xb, Wkvt, bk, bv, Kb, Vtb);

    attn<<<dim3(512), 256, 0, stream>>>(Qb, Kb, Vtb, Ctx);

    gemm_tn<3><<<dim3(NTOK / 128, HID / 128), 256, 0, stream>>>(Ctx, Wot, bo, nullptr, out, nullptr);
}